// Round 1
// baseline (542.259 us; speedup 1.0000x reference)
//
#include <hip/hip_runtime.h>
#include <hip/hip_bf16.h>

typedef __bf16 bf16x8 __attribute__((ext_vector_type(8)));
typedef float  f32x4  __attribute__((ext_vector_type(4)));

#define EPSV 1e-5f

// ---------------------------------------------------------------------------
// K1: A = x @ Wa^T, B = x @ Wb^T   (Wa = W1[:, :128], Wb = W1[:, 128:])
// grid 256 blocks x 256 thr; each block does 4 rows of x.
// ---------------------------------------------------------------------------
__global__ __launch_bounds__(256) void k_ab(const float* __restrict__ x,
                                            const float* __restrict__ W1,
                                            float* __restrict__ A,
                                            float* __restrict__ Bm) {
  __shared__ float xs[4 * 128];
  int t = threadIdx.x;
  int j0 = blockIdx.x * 4;
  for (int idx = t; idx < 512; idx += 256) xs[idx] = x[j0 * 128 + idx];
  __syncthreads();
  int h = t & 127, half = t >> 7;
  const float4* wrow = (const float4*)(W1 + h * 256 + half * 128);
  const float4* xs4 = (const float4*)xs;
  float a0 = 0.f, a1 = 0.f, a2 = 0.f, a3 = 0.f;
#pragma unroll 8
  for (int ch = 0; ch < 32; ++ch) {
    float4 wv = wrow[ch];
    float4 x0 = xs4[ch], x1 = xs4[32 + ch], x2 = xs4[64 + ch], x3 = xs4[96 + ch];
    a0 += wv.x * x0.x + wv.y * x0.y + wv.z * x0.z + wv.w * x0.w;
    a1 += wv.x * x1.x + wv.y * x1.y + wv.z * x1.z + wv.w * x1.w;
    a2 += wv.x * x2.x + wv.y * x2.y + wv.z * x2.z + wv.w * x2.w;
    a3 += wv.x * x3.x + wv.y * x3.y + wv.z * x3.z + wv.w * x3.w;
  }
  float* dst = half ? Bm : A;
  dst[(j0 + 0) * 128 + h] = a0;
  dst[(j0 + 1) * 128 + h] = a1;
  dst[(j0 + 2) * 128 + h] = a2;
  dst[(j0 + 3) * 128 + h] = a3;
}

// ---------------------------------------------------------------------------
// K2: per-channel sum / sumsq of A and B (for BN1 stats). grid 64 x 256.
// gs: [sumA(128) | sumsqA(128) | sumB(128) | sumsqB(128)] (pre-zeroed)
// ---------------------------------------------------------------------------
__global__ __launch_bounds__(256) void k_stats1(const float* __restrict__ A,
                                                const float* __restrict__ Bm,
                                                float* __restrict__ gs) {
  int t = threadIdx.x;
  int c = t & 127, rr = t >> 7;
  float sA = 0.f, qA = 0.f, sB = 0.f, qB = 0.f;
#pragma unroll
  for (int s = 0; s < 8; ++s) {
    int r = blockIdx.x * 16 + rr + s * 2;
    float a = A[r * 128 + c];  sA += a; qA += a * a;
    float b = Bm[r * 128 + c]; sB += b; qB += b * b;
  }
  atomicAdd(&gs[c], sA);
  atomicAdd(&gs[128 + c], qA);
  atomicAdd(&gs[256 + c], sB);
  atomicAdd(&gs[384 + c], qB);
}

// ---------------------------------------------------------------------------
// K3a: BN1 fold params.  h1 = relu((A-mA)*sc + be1  +  (B-mB)*sc)
// (b1 cancels inside BN).  Also converts W2 -> bf16. 1 block x 128 thr.
// scp: [sc | ta | tb]
// ---------------------------------------------------------------------------
__global__ void k_fold1(const float* __restrict__ gs, const float* __restrict__ g1,
                        const float* __restrict__ be1, const float* __restrict__ W2,
                        float* __restrict__ scp, __bf16* __restrict__ w2b) {
  int c = threadIdx.x;
  const float inv = 1.f / 1024.f;
  float mA = gs[c] * inv;
  float vA = gs[128 + c] * inv - mA * mA;
  float mB = gs[256 + c] * inv;
  float vB = gs[384 + c] * inv - mB * mB;
  float sc = g1[c] * rsqrtf(vA + vB + EPSV);
  scp[c] = sc;
  scp[128 + c] = be1[c] - mA * sc;
  scp[256 + c] = -mB * sc;
  for (int idx = c; idx < 16384; idx += 128) w2b[idx] = (__bf16)W2[idx];
}

// ---------------------------------------------------------------------------
// K3b: apply fold: At = A*sc+ta, Bt = B*sc+tb. grid 128 x 256 (float4).
// ---------------------------------------------------------------------------
__global__ __launch_bounds__(256) void k_fold1_apply(const float* __restrict__ A,
                                                     const float* __restrict__ Bm,
                                                     const float* __restrict__ scp,
                                                     float* __restrict__ At,
                                                     float* __restrict__ Bt) {
  int idx4 = blockIdx.x * 256 + threadIdx.x;  // 32768 float4s per array
  int c4 = idx4 & 31;
  const float4* s4 = (const float4*)scp;
  float4 sc = s4[c4], ta = s4[32 + c4], tb = s4[64 + c4];
  float4 a = ((const float4*)A)[idx4];
  float4 b = ((const float4*)Bm)[idx4];
  float4 oa, ob;
  oa.x = a.x * sc.x + ta.x; oa.y = a.y * sc.y + ta.y;
  oa.z = a.z * sc.z + ta.z; oa.w = a.w * sc.w + ta.w;
  ob.x = b.x * sc.x + tb.x; ob.y = b.y * sc.y + tb.y;
  ob.z = b.z * sc.z + tb.z; ob.w = b.w * sc.w + tb.w;
  ((float4*)At)[idx4] = oa;
  ((float4*)Bt)[idx4] = ob;
}

// ---------------------------------------------------------------------------
// Main pass. Tile = 8 i-rows x 16 j-rows = 128 pairs. 256 thr = 4 waves.
// h1 tile (128 x 128 bf16, rows padded to 136 to break bank-stride) in LDS.
// GEMM vs W2^T via mfma_f32_16x16x32_bf16: per wave 2 m-tiles x 8 n-tiles.
// PASS==1: accumulate per-k sum(dot), sum(dot^2) -> partials[bid*256..]
// PASS==2: fuse BN2+relu+W3 dot -> logits L[i,j]
// grid: 8192 = 128 (ti) x 64 (tj)
// ---------------------------------------------------------------------------
template <int PASS>
__global__ __launch_bounds__(256, 4) void k_pass(
    const float* __restrict__ At, const float* __restrict__ Bt,
    const __bf16* __restrict__ w2b, float* __restrict__ partials,
    const float* __restrict__ a2p, const float* __restrict__ W3v,
    const float* __restrict__ b3p, float* __restrict__ L) {
  __shared__ __bf16 H1[128 * 136];
  __shared__ float red[4 * 256];
  int t = threadIdx.x;
  int bid = blockIdx.x;
  int ti = bid >> 6, tj = bid & 63;

  // ---- build h1 tile: pair p = ii*16+jj; 2 threads per pair (64 ch each) ----
  {
    int p = t >> 1, half = t & 1;
    int ii = p >> 4, jj = p & 15;
    const float4* ra = (const float4*)(At + (tj * 16 + jj) * 128 + half * 64);
    const float4* rb = (const float4*)(Bt + (ti * 8 + ii) * 128 + half * 64);
    __bf16* dst = H1 + p * 136 + half * 64;
#pragma unroll 2
    for (int ch = 0; ch < 8; ++ch) {
      float4 a0 = ra[2 * ch], a1 = ra[2 * ch + 1];
      float4 b0 = rb[2 * ch], b1 = rb[2 * ch + 1];
      bf16x8 v;
      v[0] = (__bf16)fmaxf(a0.x + b0.x, 0.f);
      v[1] = (__bf16)fmaxf(a0.y + b0.y, 0.f);
      v[2] = (__bf16)fmaxf(a0.z + b0.z, 0.f);
      v[3] = (__bf16)fmaxf(a0.w + b0.w, 0.f);
      v[4] = (__bf16)fmaxf(a1.x + b1.x, 0.f);
      v[5] = (__bf16)fmaxf(a1.y + b1.y, 0.f);
      v[6] = (__bf16)fmaxf(a1.z + b1.z, 0.f);
      v[7] = (__bf16)fmaxf(a1.w + b1.w, 0.f);
      *(bf16x8*)(dst + ch * 8) = v;
    }
  }
  __syncthreads();

  int lane = t & 63, w = t >> 6;
  int col = lane & 15, quad = lane >> 4;

  f32x4 acc[2][8];
#pragma unroll
  for (int mt = 0; mt < 2; ++mt)
#pragma unroll
    for (int nt = 0; nt < 8; ++nt) acc[mt][nt] = (f32x4){0.f, 0.f, 0.f, 0.f};

#pragma unroll
  for (int ks = 0; ks < 4; ++ks) {
    bf16x8 af[2];
#pragma unroll
    for (int mt = 0; mt < 2; ++mt)
      af[mt] = *(const bf16x8*)(&H1[(w * 32 + mt * 16 + col) * 136 + ks * 32 + quad * 8]);
#pragma unroll
    for (int nt = 0; nt < 8; ++nt) {
      bf16x8 bv = *(const bf16x8*)(&w2b[(nt * 16 + col) * 128 + ks * 32 + quad * 8]);
#pragma unroll
      for (int mt = 0; mt < 2; ++mt)
        acc[mt][nt] = __builtin_amdgcn_mfma_f32_16x16x32_bf16(af[mt], bv, acc[mt][nt], 0, 0, 0);
    }
  }

  if (PASS == 1) {
    float s1[8], s2[8];
#pragma unroll
    for (int nt = 0; nt < 8; ++nt) { s1[nt] = 0.f; s2[nt] = 0.f; }
#pragma unroll
    for (int nt = 0; nt < 8; ++nt)
#pragma unroll
      for (int mt = 0; mt < 2; ++mt)
#pragma unroll
        for (int r = 0; r < 4; ++r) {
          float d = acc[mt][nt][r];
          s1[nt] += d;
          s2[nt] += d * d;
        }
#pragma unroll
    for (int nt = 0; nt < 8; ++nt) {
      s1[nt] += __shfl_xor(s1[nt], 16);
      s1[nt] += __shfl_xor(s1[nt], 32);
      s2[nt] += __shfl_xor(s2[nt], 16);
      s2[nt] += __shfl_xor(s2[nt], 32);
    }
    if (lane < 16) {
#pragma unroll
      for (int nt = 0; nt < 8; ++nt) {
        red[w * 256 + nt * 16 + lane] = s1[nt];
        red[w * 256 + 128 + nt * 16 + lane] = s2[nt];
      }
    }
    __syncthreads();
    float tot = red[t] + red[256 + t] + red[512 + t] + red[768 + t];
    partials[bid * 256 + t] = tot;
  } else {
    float b3v = b3p[0];
    float al[8], uu[8], w3l[8];
#pragma unroll
    for (int nt = 0; nt < 8; ++nt) {
      int k = nt * 16 + col;
      al[nt] = a2p[k];
      uu[nt] = a2p[128 + k];
      w3l[nt] = W3v[k];
    }
#pragma unroll
    for (int mt = 0; mt < 2; ++mt) {
      float rsum[4] = {0.f, 0.f, 0.f, 0.f};
#pragma unroll
      for (int nt = 0; nt < 8; ++nt)
#pragma unroll
        for (int r = 0; r < 4; ++r) {
          float h = fmaxf(acc[mt][nt][r] * al[nt] + uu[nt], 0.f);
          rsum[r] += h * w3l[nt];
        }
#pragma unroll
      for (int r = 0; r < 4; ++r) {
        rsum[r] += __shfl_xor(rsum[r], 1);
        rsum[r] += __shfl_xor(rsum[r], 2);
        rsum[r] += __shfl_xor(rsum[r], 4);
        rsum[r] += __shfl_xor(rsum[r], 8);
      }
      if (col == 0) {
#pragma unroll
        for (int r = 0; r < 4; ++r) {
          int m = w * 32 + mt * 16 + quad * 4 + r;  // pair index in tile
          int ii = m >> 4, jj = m & 15;
          L[(ti * 8 + ii) * 1024 + tj * 16 + jj] = rsum[r] + b3v;
        }
      }
    }
  }
}

// ---------------------------------------------------------------------------
// K5a: reduce pass-1 partials (8192 x 256) -> sum2[256]. grid 512 x 256.
// ---------------------------------------------------------------------------
__global__ __launch_bounds__(256) void k_red_partials(const float* __restrict__ partials,
                                                      float* __restrict__ sum2) {
  int t = threadIdx.x;
  float s = 0.f;
  int r0 = blockIdx.x * 16;
#pragma unroll
  for (int r = 0; r < 16; ++r) s += partials[(r0 + r) * 256 + t];
  atomicAdd(&sum2[t], s);
}

// ---------------------------------------------------------------------------
// K5b: BN2 fold params (b2 cancels). a2p: [alpha2 | u2]. 1 block x 128 thr.
// ---------------------------------------------------------------------------
__global__ void k_fold2(const float* __restrict__ sum2, const float* __restrict__ g2,
                        const float* __restrict__ be2, float* __restrict__ a2p) {
  int k = threadIdx.x;
  const float invM = 1.f / (1024.f * 1024.f);
  float mdot = sum2[k] * invM;
  float var = sum2[128 + k] * invM - mdot * mdot;
  float al = g2[k] * rsqrtf(var + EPSV);
  a2p[k] = al;
  a2p[128 + k] = be2[k] - mdot * al;
}

// ---------------------------------------------------------------------------
// K7: adj[i,j] = (i==j) ? 0 : sigmoid(0.5*(L[i,j]+L[j,i])). grid 4096 x 256.
// ---------------------------------------------------------------------------
__global__ __launch_bounds__(256) void k_adj(const float* __restrict__ L,
                                             float* __restrict__ out) {
  int idx = blockIdx.x * 256 + threadIdx.x;
  int i = idx >> 10, j = idx & 1023;
  float a = L[i * 1024 + j];
  float b = L[j * 1024 + i];
  float s = 1.f / (1.f + __expf(-0.5f * (a + b)));
  out[idx] = (i == j) ? 0.f : s;
}

// ---------------------------------------------------------------------------
extern "C" void kernel_launch(void* const* d_in, const int* in_sizes, int n_in,
                              void* d_out, int out_size, void* d_ws, size_t ws_size,
                              hipStream_t stream) {
  const float* x   = (const float*)d_in[0];
  const float* W1  = (const float*)d_in[1];
  // d_in[2] = b1 : cancels inside BN1, unused
  const float* W2  = (const float*)d_in[3];
  // d_in[4] = b2 : cancels inside BN2, unused
  const float* W3  = (const float*)d_in[5];
  const float* b3  = (const float*)d_in[6];
  const float* g1  = (const float*)d_in[7];
  const float* be1 = (const float*)d_in[8];
  const float* g2  = (const float*)d_in[9];
  const float* be2 = (const float*)d_in[10];

  float* ws = (float*)d_ws;
  float* A        = ws;                 // 131072
  float* Bm       = ws + 131072;        // 131072
  float* At       = ws + 262144;        // 131072
  float* Bt       = ws + 393216;        // 131072
  __bf16* w2b     = (__bf16*)(ws + 524288);  // 16384 bf16 = 8192 floats
  float* gs       = ws + 532480;        // 512
  float* scp      = ws + 532992;        // 384
  float* a2p      = ws + 533376;        // 256
  float* sum2     = ws + 533632;        // 256
  float* partials = ws + 533888;        // 8192*256 = 2097152
  float* L        = ws + 2631040;       // 1048576
  float* out      = (float*)d_out;

  hipMemsetAsync(gs, 0, 512 * sizeof(float), stream);
  hipMemsetAsync(sum2, 0, 256 * sizeof(float), stream);

  k_ab<<<256, 256, 0, stream>>>(x, W1, A, Bm);
  k_stats1<<<64, 256, 0, stream>>>(A, Bm, gs);
  k_fold1<<<1, 128, 0, stream>>>(gs, g1, be1, W2, scp, w2b);
  k_fold1_apply<<<128, 256, 0, stream>>>(A, Bm, scp, At, Bt);
  k_pass<1><<<8192, 256, 0, stream>>>(At, Bt, w2b, partials, nullptr, nullptr, nullptr, nullptr);
  k_red_partials<<<512, 256, 0, stream>>>(partials, sum2);
  k_fold2<<<1, 128, 0, stream>>>(sum2, g2, be2, a2p);
  k_pass<2><<<8192, 256, 0, stream>>>(At, Bt, w2b, nullptr, a2p, W3, b3, L);
  k_adj<<<4096, 256, 0, stream>>>(L, out);
}

// Round 2
// 269.664 us; speedup vs baseline: 2.0109x; 2.0109x over previous
//
#include <hip/hip_runtime.h>
#include <hip/hip_bf16.h>

typedef __bf16 bf16x8 __attribute__((ext_vector_type(8)));
typedef float  f32x4  __attribute__((ext_vector_type(4)));
typedef float  f32x8  __attribute__((ext_vector_type(8)));

#define EPSV 1e-5f

// ---------------------------------------------------------------------------
// K1: A = x @ Wa^T, B = x @ Wb^T   (Wa = W1[:, :128], Wb = W1[:, 128:])
// grid 256 blocks x 256 thr; each block does 4 rows of x.
// ---------------------------------------------------------------------------
__global__ __launch_bounds__(256) void k_ab(const float* __restrict__ x,
                                            const float* __restrict__ W1,
                                            float* __restrict__ A,
                                            float* __restrict__ Bm) {
  __shared__ float xs[4 * 128];
  int t = threadIdx.x;
  int j0 = blockIdx.x * 4;
  for (int idx = t; idx < 512; idx += 256) xs[idx] = x[j0 * 128 + idx];
  __syncthreads();
  int h = t & 127, half = t >> 7;
  const float4* wrow = (const float4*)(W1 + h * 256 + half * 128);
  const float4* xs4 = (const float4*)xs;
  float a0 = 0.f, a1 = 0.f, a2 = 0.f, a3 = 0.f;
#pragma unroll 8
  for (int ch = 0; ch < 32; ++ch) {
    float4 wv = wrow[ch];
    float4 x0 = xs4[ch], x1 = xs4[32 + ch], x2 = xs4[64 + ch], x3 = xs4[96 + ch];
    a0 += wv.x * x0.x + wv.y * x0.y + wv.z * x0.z + wv.w * x0.w;
    a1 += wv.x * x1.x + wv.y * x1.y + wv.z * x1.z + wv.w * x1.w;
    a2 += wv.x * x2.x + wv.y * x2.y + wv.z * x2.z + wv.w * x2.w;
    a3 += wv.x * x3.x + wv.y * x3.y + wv.z * x3.z + wv.w * x3.w;
  }
  float* dst = half ? Bm : A;
  dst[(j0 + 0) * 128 + h] = a0;
  dst[(j0 + 1) * 128 + h] = a1;
  dst[(j0 + 2) * 128 + h] = a2;
  dst[(j0 + 3) * 128 + h] = a3;
}

// ---------------------------------------------------------------------------
// K2: per-channel sum / sumsq of A and B (for BN1 stats). grid 64 x 256.
// ---------------------------------------------------------------------------
__global__ __launch_bounds__(256) void k_stats1(const float* __restrict__ A,
                                                const float* __restrict__ Bm,
                                                float* __restrict__ gs) {
  int t = threadIdx.x;
  int c = t & 127, rr = t >> 7;
  float sA = 0.f, qA = 0.f, sB = 0.f, qB = 0.f;
#pragma unroll
  for (int s = 0; s < 8; ++s) {
    int r = blockIdx.x * 16 + rr + s * 2;
    float a = A[r * 128 + c];  sA += a; qA += a * a;
    float b = Bm[r * 128 + c]; sB += b; qB += b * b;
  }
  atomicAdd(&gs[c], sA);
  atomicAdd(&gs[128 + c], qA);
  atomicAdd(&gs[256 + c], sB);
  atomicAdd(&gs[384 + c], qB);
}

// ---------------------------------------------------------------------------
// K3a: BN1 fold params + W2 -> bf16. 1 block x 128 thr.
// ---------------------------------------------------------------------------
__global__ void k_fold1(const float* __restrict__ gs, const float* __restrict__ g1,
                        const float* __restrict__ be1, const float* __restrict__ W2,
                        float* __restrict__ scp, __bf16* __restrict__ w2b) {
  int c = threadIdx.x;
  const float inv = 1.f / 1024.f;
  float mA = gs[c] * inv;
  float vA = gs[128 + c] * inv - mA * mA;
  float mB = gs[256 + c] * inv;
  float vB = gs[384 + c] * inv - mB * mB;
  float sc = g1[c] * rsqrtf(vA + vB + EPSV);
  scp[c] = sc;
  scp[128 + c] = be1[c] - mA * sc;
  scp[256 + c] = -mB * sc;
  for (int idx = c; idx < 16384; idx += 128) w2b[idx] = (__bf16)W2[idx];
}

// ---------------------------------------------------------------------------
// K3b: At = A*sc+ta, Bt = B*sc+tb. grid 128 x 256 (float4).
// ---------------------------------------------------------------------------
__global__ __launch_bounds__(256) void k_fold1_apply(const float* __restrict__ A,
                                                     const float* __restrict__ Bm,
                                                     const float* __restrict__ scp,
                                                     float* __restrict__ At,
                                                     float* __restrict__ Bt) {
  int idx4 = blockIdx.x * 256 + threadIdx.x;
  int c4 = idx4 & 31;
  const float4* s4 = (const float4*)scp;
  float4 sc = s4[c4], ta = s4[32 + c4], tb = s4[64 + c4];
  float4 a = ((const float4*)A)[idx4];
  float4 b = ((const float4*)Bm)[idx4];
  float4 oa, ob;
  oa.x = a.x * sc.x + ta.x; oa.y = a.y * sc.y + ta.y;
  oa.z = a.z * sc.z + ta.z; oa.w = a.w * sc.w + ta.w;
  ob.x = b.x * sc.x + tb.x; ob.y = b.y * sc.y + tb.y;
  ob.z = b.z * sc.z + tb.z; ob.w = b.w * sc.w + tb.w;
  ((float4*)At)[idx4] = oa;
  ((float4*)Bt)[idx4] = ob;
}

// ---------------------------------------------------------------------------
// h1 A-fragment built directly in registers: h1[j][k] = relu(At[j][k]+Bt[i][k])
// for k = off..off+8. Packed f32 math -> packed bf16 convert.
// ---------------------------------------------------------------------------
__device__ __forceinline__ bf16x8 build_h1(const float* __restrict__ arow,
                                           const float* __restrict__ brow,
                                           int off) {
  f32x4 a0 = *(const f32x4*)(arow + off);
  f32x4 a1 = *(const f32x4*)(arow + off + 4);
  f32x4 b0 = *(const f32x4*)(brow + off);
  f32x4 b1 = *(const f32x4*)(brow + off + 4);
  f32x4 z = {0.f, 0.f, 0.f, 0.f};
  f32x4 h0 = __builtin_elementwise_max(a0 + b0, z);
  f32x4 h1 = __builtin_elementwise_max(a1 + b1, z);
  f32x8 h = __builtin_shufflevector(h0, h1, 0, 1, 2, 3, 4, 5, 6, 7);
  return __builtin_convertvector(h, bf16x8);
}

// ---------------------------------------------------------------------------
// Main pass, no-LDS register design.
// Block = 4 waves. Wave handles i-rows {bi*8+w*2, +1}, j-cols bj*128..+128
// via 8 subtiles of 16. W2 fragments (all 32) preloaded to registers once.
// grid 1024 = bi(128) x bj(8); bj = bid&7 -> XCD-local At slice.
// PASS1: accumulate per-k sum(dot), sum(dot^2) -> partials[bid*256..]
// PASS2: fuse BN2+relu+W3 dot -> logits L[i,j]
// ---------------------------------------------------------------------------
template <int PASS>
__global__ __launch_bounds__(256) void k_pass(
    const float* __restrict__ At, const float* __restrict__ Bt,
    const __bf16* __restrict__ w2b, float* __restrict__ partials,
    const float* __restrict__ a2p, const float* __restrict__ W3v,
    const float* __restrict__ b3p, float* __restrict__ L) {
  __shared__ float red[4 * 256];
  int t = threadIdx.x;
  int bid = blockIdx.x;
  int bj = bid & 7, bi = bid >> 3;
  int lane = t & 63, w = t >> 6;
  int col = lane & 15, quad = lane >> 4;

  // ---- preload all W2 fragments: bw[ks][nt], 128 VGPRs, reused 8x ----
  bf16x8 bw[4][8];
#pragma unroll
  for (int ks = 0; ks < 4; ++ks)
#pragma unroll
    for (int nt = 0; nt < 8; ++nt)
      bw[ks][nt] = *(const bf16x8*)(w2b + (nt * 16 + col) * 128 + ks * 32 + quad * 8);

  const float* brow0 = Bt + (bi * 8 + w * 2) * 128;
  const float* brow1 = brow0 + 128;
  const float* acol  = At + (bj * 128 + col) * 128;

  float s1[8], s2[8];
  float al[8], uu[8], w3l[8];
  float b3v = 0.f;
  if (PASS == 1) {
#pragma unroll
    for (int nt = 0; nt < 8; ++nt) { s1[nt] = 0.f; s2[nt] = 0.f; }
  } else {
    b3v = b3p[0];
#pragma unroll
    for (int nt = 0; nt < 8; ++nt) {
      int k = nt * 16 + col;
      al[nt] = a2p[k];
      uu[nt] = a2p[128 + k];
      w3l[nt] = W3v[k];
    }
  }

  for (int s = 0; s < 8; ++s) {
    const float* arow = acol + s * 16 * 128;
    f32x4 acc[2][8];
#pragma unroll
    for (int mt = 0; mt < 2; ++mt)
#pragma unroll
      for (int nt = 0; nt < 8; ++nt) acc[mt][nt] = (f32x4){0.f, 0.f, 0.f, 0.f};

#pragma unroll
    for (int ks = 0; ks < 4; ++ks) {
      int off = ks * 32 + quad * 8;
      bf16x8 a0 = build_h1(arow, brow0, off);
      bf16x8 a1 = build_h1(arow, brow1, off);
#pragma unroll
      for (int nt = 0; nt < 8; ++nt) {
        acc[0][nt] = __builtin_amdgcn_mfma_f32_16x16x32_bf16(a0, bw[ks][nt], acc[0][nt], 0, 0, 0);
        acc[1][nt] = __builtin_amdgcn_mfma_f32_16x16x32_bf16(a1, bw[ks][nt], acc[1][nt], 0, 0, 0);
      }
    }

    if (PASS == 1) {
#pragma unroll
      for (int nt = 0; nt < 8; ++nt)
#pragma unroll
        for (int mt = 0; mt < 2; ++mt)
#pragma unroll
          for (int r = 0; r < 4; ++r) {
            float d = acc[mt][nt][r];
            s1[nt] += d;
            s2[nt] = fmaf(d, d, s2[nt]);
          }
    } else {
#pragma unroll
      for (int mt = 0; mt < 2; ++mt) {
        float rsum[4] = {0.f, 0.f, 0.f, 0.f};
#pragma unroll
        for (int nt = 0; nt < 8; ++nt)
#pragma unroll
          for (int r = 0; r < 4; ++r) {
            float h = fmaxf(fmaf(acc[mt][nt][r], al[nt], uu[nt]), 0.f);
            rsum[r] = fmaf(h, w3l[nt], rsum[r]);
          }
#pragma unroll
        for (int r = 0; r < 4; ++r) {
          rsum[r] += __shfl_xor(rsum[r], 1);
          rsum[r] += __shfl_xor(rsum[r], 2);
          rsum[r] += __shfl_xor(rsum[r], 4);
          rsum[r] += __shfl_xor(rsum[r], 8);
        }
        if (col == 0) {
          int i = bi * 8 + w * 2 + mt;
#pragma unroll
          for (int r = 0; r < 4; ++r)
            L[i * 1024 + bj * 128 + s * 16 + quad * 4 + r] = rsum[r] + b3v;
        }
      }
    }
  }

  if (PASS == 1) {
#pragma unroll
    for (int nt = 0; nt < 8; ++nt) {
      s1[nt] += __shfl_xor(s1[nt], 16);
      s1[nt] += __shfl_xor(s1[nt], 32);
      s2[nt] += __shfl_xor(s2[nt], 16);
      s2[nt] += __shfl_xor(s2[nt], 32);
    }
    if (lane < 16) {
#pragma unroll
      for (int nt = 0; nt < 8; ++nt) {
        red[w * 256 + nt * 16 + lane] = s1[nt];
        red[w * 256 + 128 + nt * 16 + lane] = s2[nt];
      }
    }
    __syncthreads();
    float tot = red[t] + red[256 + t] + red[512 + t] + red[768 + t];
    partials[bid * 256 + t] = tot;
  }
}

// ---------------------------------------------------------------------------
// K5a: reduce pass-1 partials (1024 x 256) -> sum2[256]. grid 64 x 256.
// ---------------------------------------------------------------------------
__global__ __launch_bounds__(256) void k_red_partials(const float* __restrict__ partials,
                                                      float* __restrict__ sum2) {
  int t = threadIdx.x;
  float s = 0.f;
  int r0 = blockIdx.x * 16;
#pragma unroll
  for (int r = 0; r < 16; ++r) s += partials[(r0 + r) * 256 + t];
  atomicAdd(&sum2[t], s);
}

// ---------------------------------------------------------------------------
// K5b: BN2 fold params. a2p: [alpha2 | u2]. 1 block x 128 thr.
// ---------------------------------------------------------------------------
__global__ void k_fold2(const float* __restrict__ sum2, const float* __restrict__ g2,
                        const float* __restrict__ be2, float* __restrict__ a2p) {
  int k = threadIdx.x;
  const float invM = 1.f / (1024.f * 1024.f);
  float mdot = sum2[k] * invM;
  float var = sum2[128 + k] * invM - mdot * mdot;
  float al = g2[k] * rsqrtf(var + EPSV);
  a2p[k] = al;
  a2p[128 + k] = be2[k] - mdot * al;
}

// ---------------------------------------------------------------------------
// K7: adj[i,j] = (i==j) ? 0 : sigmoid(0.5*(L[i,j]+L[j,i])). grid 4096 x 256.
// ---------------------------------------------------------------------------
__global__ __launch_bounds__(256) void k_adj(const float* __restrict__ L,
                                             float* __restrict__ out) {
  int idx = blockIdx.x * 256 + threadIdx.x;
  int i = idx >> 10, j = idx & 1023;
  float a = L[i * 1024 + j];
  float b = L[j * 1024 + i];
  float s = 1.f / (1.f + __expf(-0.5f * (a + b)));
  out[idx] = (i == j) ? 0.f : s;
}

// ---------------------------------------------------------------------------
extern "C" void kernel_launch(void* const* d_in, const int* in_sizes, int n_in,
                              void* d_out, int out_size, void* d_ws, size_t ws_size,
                              hipStream_t stream) {
  const float* x   = (const float*)d_in[0];
  const float* W1  = (const float*)d_in[1];
  const float* W2  = (const float*)d_in[3];
  const float* W3  = (const float*)d_in[5];
  const float* b3  = (const float*)d_in[6];
  const float* g1  = (const float*)d_in[7];
  const float* be1 = (const float*)d_in[8];
  const float* g2  = (const float*)d_in[9];
  const float* be2 = (const float*)d_in[10];

  float* ws = (float*)d_ws;
  float* A        = ws;                 // 131072
  float* Bm       = ws + 131072;        // 131072
  float* At       = ws + 262144;        // 131072
  float* Bt       = ws + 393216;        // 131072
  __bf16* w2b     = (__bf16*)(ws + 524288);  // 16384 bf16
  float* gs       = ws + 532480;        // 512
  float* scp      = ws + 532992;        // 384
  float* a2p      = ws + 533376;        // 256
  float* sum2     = ws + 533632;        // 256
  float* partials = ws + 533888;        // 1024*256 = 262144
  float* L        = ws + 796032;        // 1048576
  float* out      = (float*)d_out;

  hipMemsetAsync(gs, 0, 512 * sizeof(float), stream);
  hipMemsetAsync(sum2, 0, 256 * sizeof(float), stream);

  k_ab<<<256, 256, 0, stream>>>(x, W1, A, Bm);
  k_stats1<<<64, 256, 0, stream>>>(A, Bm, gs);
  k_fold1<<<1, 128, 0, stream>>>(gs, g1, be1, W2, scp, w2b);
  k_fold1_apply<<<128, 256, 0, stream>>>(A, Bm, scp, At, Bt);
  k_pass<1><<<1024, 256, 0, stream>>>(At, Bt, w2b, partials, nullptr, nullptr, nullptr, nullptr);
  k_red_partials<<<64, 256, 0, stream>>>(partials, sum2);
  k_fold2<<<1, 128, 0, stream>>>(sum2, g2, be2, a2p);
  k_pass<2><<<1024, 256, 0, stream>>>(At, Bt, w2b, nullptr, a2p, W3, b3, L);
  k_adj<<<4096, 256, 0, stream>>>(L, out);
}